// Round 11
// baseline (2447.354 us; speedup 1.0000x reference)
//
#include <hip/hip_runtime.h>
#include <hip/hip_fp16.h>
#include <cstdint>
#include <cstddef>

// GCN_EW: 2-layer GCN, exp edge weights, gcn_norm w/ self-loops, training BN,
// 64->1 head.  B=2, N=50000, E=800000, IN=128, HID=64.
//
// R11: R10 (348us) minus the two k_scsh kernels: scsh reduction folded into
// k_agg's tail via a last-64-finishers pattern (ticket from done counter;
// ranks G-64..G-1 spin until done==G then reduce one channel each).
// Deadlock-free: only 64 resident blocks spin; all other blocks are already
// executing and increment done on retirement. NOT a grid barrier (R8 lesson:
// all-block spin = ~100us/barrier). Overflow slow path: rank G-1 alone does
// CAS fixes + full exact recompute (never taken for this input).
// Dispatches 9 -> 7 (~12us/boundary measured).
// Row order r = node*2 + b (batch-fused gather, fp16 intermediates).

#define CAP  64
#define OCAP 65536
#define BN_EPS 1e-5f

static __device__ __forceinline__ unsigned h2u(__half2 h) {
  union { __half2 h; unsigned u; } c; c.h = h; return c.u;
}
static __device__ __forceinline__ __half2 u2h(unsigned u) {
  union { unsigned u; __half2 h; } c; c.u = u; return c.h;
}
static __device__ __forceinline__ unsigned pack_pair(int src, float w) {
  __half hw = __float2half_rn(w);
  union { __half h; unsigned short s; } c; c.h = hw;
  return ((unsigned)src << 16) | c.s;
}
static __device__ __forceinline__ float pair_w(unsigned p) {
  union { unsigned short s; __half h; } c; c.s = (unsigned short)(p & 0xFFFFu);
  return __half2float(c.h);
}

// ---- mega: role-striped fill (1 edge/thread) + layer-1 GEMM ----
__global__ void k_mega(const float* __restrict__ x, const float* __restrict__ W,
                       __half* __restrict__ out, int nrows, int N,
                       const float* __restrict__ ew, const int* __restrict__ ei,
                       int* __restrict__ cnt, unsigned* __restrict__ pairs,
                       int* __restrict__ ofl_cnt, int* __restrict__ ofl_list,
                       int E, int gemmBlocks, int fillBlocks) {
  constexpr int RT = 64, KC = 64, S = KC + 4;
  __shared__ float ws[KC * 64];
  __shared__ float xs[RT * S];

  int bid = blockIdx.x;
  int tid = threadIdx.x;
  int role = bid % 3;

  if (role == 0) {
    int gid = bid / 3;
    if (gid >= gemmBlocks) return;
    int row0 = gid * RT;
    int rg = tid >> 4, cg = tid & 15;
    int c0 = cg * 4, r0 = rg * 4;
    float acc[4][4];
#pragma unroll
    for (int i = 0; i < 4; ++i)
#pragma unroll
      for (int j = 0; j < 4; ++j) acc[i][j] = 0.0f;

    for (int ch = 0; ch < 2; ++ch) {
      if (ch) __syncthreads();
      const float4* Wp = (const float4*)(W + (size_t)ch * KC * 64);
      for (int s = tid; s < KC * 16; s += 256)
        ((float4*)ws)[s] = Wp[s];
      for (int s = tid; s < RT * 16; s += 256) {
        int r = s >> 4, k4 = s & 15;
        int gr = row0 + r;
        float4 v = make_float4(0.f, 0.f, 0.f, 0.f);
        if (gr < nrows)
          v = *(const float4*)(x + (size_t)gr * 128 + ch * KC + k4 * 4);
        *(float4*)&xs[r * S + k4 * 4] = v;
      }
      __syncthreads();
#pragma unroll 2
      for (int kk = 0; kk < KC; kk += 4) {
        float4 wv0 = *(const float4*)&ws[(kk + 0) * 64 + c0];
        float4 wv1 = *(const float4*)&ws[(kk + 1) * 64 + c0];
        float4 wv2 = *(const float4*)&ws[(kk + 2) * 64 + c0];
        float4 wv3 = *(const float4*)&ws[(kk + 3) * 64 + c0];
#pragma unroll
        for (int i = 0; i < 4; ++i) {
          float4 xv = *(const float4*)&xs[(r0 + i) * S + kk];
          acc[i][0] = fmaf(xv.x, wv0.x, acc[i][0]);
          acc[i][1] = fmaf(xv.x, wv0.y, acc[i][1]);
          acc[i][2] = fmaf(xv.x, wv0.z, acc[i][2]);
          acc[i][3] = fmaf(xv.x, wv0.w, acc[i][3]);
          acc[i][0] = fmaf(xv.y, wv1.x, acc[i][0]);
          acc[i][1] = fmaf(xv.y, wv1.y, acc[i][1]);
          acc[i][2] = fmaf(xv.y, wv1.z, acc[i][2]);
          acc[i][3] = fmaf(xv.y, wv1.w, acc[i][3]);
          acc[i][0] = fmaf(xv.z, wv2.x, acc[i][0]);
          acc[i][1] = fmaf(xv.z, wv2.y, acc[i][1]);
          acc[i][2] = fmaf(xv.z, wv2.z, acc[i][2]);
          acc[i][3] = fmaf(xv.z, wv2.w, acc[i][3]);
          acc[i][0] = fmaf(xv.w, wv3.x, acc[i][0]);
          acc[i][1] = fmaf(xv.w, wv3.y, acc[i][1]);
          acc[i][2] = fmaf(xv.w, wv3.z, acc[i][2]);
          acc[i][3] = fmaf(xv.w, wv3.w, acc[i][3]);
        }
      }
    }
#pragma unroll
    for (int i = 0; i < 4; ++i) {
      int gr = row0 + r0 + i;
      if (gr < nrows) {
        int orow = (gr < N) ? gr * 2 : (gr - N) * 2 + 1;
        __half2 h01 = __floats2half2_rn(acc[i][0], acc[i][1]);
        __half2 h23 = __floats2half2_rn(acc[i][2], acc[i][3]);
        *(uint2*)(out + (size_t)orow * 64 + c0) = make_uint2(h2u(h01), h2u(h23));
      }
    }
  } else {
    int fid = (bid / 3) * 2 + role - 1;
    if (fid >= fillBlocks) return;
    int e = fid * 256 + tid;
    if (e >= E) return;
    int r = ei[e];
    int c = ei[(size_t)E + e];
    float w = expf(ew[e]);
    int pos = atomicAdd(&cnt[c], 1);
    if (pos < CAP) {
      pairs[(size_t)c * CAP + pos] = pack_pair(r, w);
    } else {
      int o = atomicAdd(ofl_cnt, 1);
      if (o < OCAP) ofl_list[o] = e;
    }
  }
}

// dinv[node] = rsqrt(1+sum expw); done-counter last block handles the
// overflow slow path (adds + rsqrt) -- uniform no-op when tot==0.
__global__ void k_degb(const unsigned* __restrict__ pairs, const int* __restrict__ cnt,
                       const int* __restrict__ ofl_cnt, float* __restrict__ deg,
                       int* __restrict__ done, int N,
                       const float* __restrict__ ew, const int* __restrict__ ei,
                       const int* __restrict__ ofl_list, int E) {
  int tid = threadIdx.x;
  int node = blockIdx.x * 4 + (tid >> 6);
  int lane = tid & 63;
  int tot = *ofl_cnt;
  if (node < N) {
    int n = cnt[node];
    n = n > CAP ? CAP : n;
    float v = 0.0f;
    if (lane < n) v = pair_w(pairs[(size_t)node * CAP + lane]);
#pragma unroll
    for (int off = 32; off > 0; off >>= 1) v += __shfl_xor(v, off, 64);
    if (lane == 0) deg[node] = (tot == 0) ? rsqrtf(v + 1.0f) : (v + 1.0f);
  }
  if (tot == 0) return;                 // fast path: done
  if (tot > OCAP) tot = OCAP;
  __shared__ int isLast;
  __threadfence();
  if (tid == 0) isLast = (atomicAdd(done, 1) == (int)gridDim.x - 1);
  __syncthreads();
  if (!isLast) return;
  for (int i = tid; i < tot; i += 256) {
    int e = ofl_list[i];
    atomicAdd(&deg[ei[(size_t)E + e]], expf(ew[e]));
  }
  __threadfence();
  __syncthreads();
  for (int i = tid; i < N; i += 256) deg[i] = rsqrtf(deg[i]);
}

// ---- agg: R7 loop (1 node/wave, 12+4) + pst partials + finisher-tail scsh ----
__global__ void k_agg(const __half* __restrict__ h, const unsigned* __restrict__ pairs,
                      const int* __restrict__ cnt, const float* __restrict__ dinv,
                      __half* __restrict__ raw, const float* __restrict__ bias,
                      float* __restrict__ pst, int N, int* __restrict__ done,
                      const float* __restrict__ g, const float* __restrict__ be,
                      float* __restrict__ scsh, float invCnt,
                      const float* __restrict__ ew, const int* __restrict__ ei,
                      const int* __restrict__ oflc, const int* __restrict__ ofll,
                      int rows, int E) {
  __shared__ float Ss[64][9], Qq[64][9];
  __shared__ float TS[256], TQ[256];
  __shared__ int rank_s;
  const int tid = threadIdx.x, lane = tid & 63;
  int node = blockIdx.x * 4 + (tid >> 6);
  const __half2* hv = (const __half2*)h;
  int ch0 = 2 * (lane & 31);
  float sx = 0.f, sy = 0.f, qx = 0.f, qy = 0.f;

  if (node < N) {
    float dc = dinv[node];
    float2 self = __half22float2(hv[(size_t)node * 64 + lane]);
    float ax = self.x * dc, ay = self.y * dc;
    int n = cnt[node];
    n = n > CAP ? CAP : n;
    const unsigned* pp = pairs + (size_t)node * CAP;
    int k = 0;
    for (; k + 12 <= n; k += 12) {
      unsigned pr[12];
#pragma unroll
      for (int q = 0; q < 12; ++q) pr[q] = pp[k + q];
      float dr[12];
#pragma unroll
      for (int q = 0; q < 12; ++q) dr[q] = dinv[pr[q] >> 16];
      __half2 v[12];
#pragma unroll
      for (int q = 0; q < 12; ++q) v[q] = hv[(size_t)(pr[q] >> 16) * 64 + lane];
#pragma unroll
      for (int q = 0; q < 12; ++q) {
        float w = pair_w(pr[q]) * dr[q];
        float2 f = __half22float2(v[q]);
        ax = fmaf(w, f.x, ax);
        ay = fmaf(w, f.y, ay);
      }
    }
    for (; k + 4 <= n; k += 4) {
      unsigned pr[4];
#pragma unroll
      for (int q = 0; q < 4; ++q) pr[q] = pp[k + q];
      float dr[4];
#pragma unroll
      for (int q = 0; q < 4; ++q) dr[q] = dinv[pr[q] >> 16];
      __half2 v[4];
#pragma unroll
      for (int q = 0; q < 4; ++q) v[q] = hv[(size_t)(pr[q] >> 16) * 64 + lane];
#pragma unroll
      for (int q = 0; q < 4; ++q) {
        float w = pair_w(pr[q]) * dr[q];
        float2 f = __half22float2(v[q]);
        ax = fmaf(w, f.x, ax);
        ay = fmaf(w, f.y, ay);
      }
    }
    for (; k < n; ++k) {
      unsigned pr = pp[k];
      float w = pair_w(pr) * dinv[pr >> 16];
      float2 f = __half22float2(hv[(size_t)(pr >> 16) * 64 + lane]);
      ax = fmaf(w, f.x, ax);
      ay = fmaf(w, f.y, ay);
    }
    __half2 r = __floats2half2_rn(ax * dc, ay * dc);
    ((__half2*)raw)[(size_t)node * 64 + lane] = r;
    float2 f = __half22float2(r);          // stats on stored (rounded) values
    float bb0 = bias[ch0], bb1 = bias[ch0 + 1];
    float y0 = fmaxf(f.x + bb0, 0.f), y1 = fmaxf(f.y + bb1, 0.f);
    sx = y0; qx = y0 * y0; sy = y1; qy = y1 * y1;
  }

  int j = tid >> 5;                        // 8 groups; (ch0,j) writer unique
  Ss[ch0][j] = sx; Ss[ch0 + 1][j] = sy;
  Qq[ch0][j] = qx; Qq[ch0 + 1][j] = qy;
  __syncthreads();
  if (tid < 64) {
    float s = 0.f, q = 0.f;
#pragma unroll
    for (int u = 0; u < 8; ++u) { s += Ss[tid][u]; q += Qq[tid][u]; }
    pst[(size_t)blockIdx.x * 128 + tid] = s;
    pst[(size_t)blockIdx.x * 128 + 64 + tid] = q;
  }

  // ---- finisher tail: last 64 blocks reduce pst -> scsh ----
  const int G = (int)gridDim.x;
  __threadfence();
  if (tid == 0) rank_s = atomicAdd(done, 1);
  __syncthreads();
  int rank = rank_s;
  if (rank < G - 64) return;
  if (tid == 0) {
    while (atomicAdd(done, 0) < G) __builtin_amdgcn_s_sleep(8);
  }
  __syncthreads();
  __threadfence();

  int tot = *oflc;
  if (tot > OCAP) tot = OCAP;
  int mych = rank - (G - 64);              // 0..63, unique per tail block

  if (tot == 0) {
    float s = 0.f, q = 0.f;
    for (int b = tid; b < G; b += 256) {
      s += pst[(size_t)b * 128 + mych];
      q += pst[(size_t)b * 128 + 64 + mych];
    }
    TS[tid] = s; TQ[tid] = q;
    __syncthreads();
    for (int o = 128; o; o >>= 1) {
      if (tid < o) { TS[tid] += TS[tid + o]; TQ[tid] += TQ[tid + o]; }
      __syncthreads();
    }
    if (tid == 0) {
      float m = TS[0] * invCnt;
      float v = TQ[0] * invCnt - m * m;
      v = v < 0.f ? 0.f : v;
      float inv = rsqrtf(v + BN_EPS);
      float sc = g[mych] * inv;
      scsh[mych] = sc;
      scsh[64 + mych] = be[mych] - m * sc;
    }
    return;
  }

  // slow path (never taken for this input): rank G-1 alone does CAS fixes
  // on raw, then full exact stats + scsh.
  if (rank != G - 1) return;
  for (int i = tid; i < tot; i += 256) {
    int e = ofll[i];
    int r = ei[e], c = ei[(size_t)E + e];
    float nrm = dinv[r] * expf(ew[e]) * dinv[c];
    const __half2* hr = (const __half2*)(h + (size_t)r * 128);
    unsigned* dst = (unsigned*)(raw + (size_t)c * 128);
    for (int jj = 0; jj < 64; ++jj) {
      float2 hv2 = __half22float2(hr[jj]);
      unsigned old = dst[jj], assumed;
      do {
        assumed = old;
        float2 cur = __half22float2(u2h(assumed));
        __half2 nv = __floats2half2_rn(cur.x + nrm * hv2.x, cur.y + nrm * hv2.y);
        old = atomicCAS(&dst[jj], assumed, h2u(nv));
      } while (old != assumed);
    }
  }
  __threadfence();
  __syncthreads();
  {
    int c = tid & 63, rg = tid >> 6;
    float s2 = 0.f, q2 = 0.f;
    for (int r = rg; r < rows; r += 4) {
      float y = fmaxf(__half2float(raw[(size_t)r * 64 + c]) + bias[c], 0.f);
      s2 += y; q2 += y * y;
    }
    TS[tid] = s2; TQ[tid] = q2;
    __syncthreads();
    if (tid < 64) {
      float ts = TS[tid] + TS[tid + 64] + TS[tid + 128] + TS[tid + 192];
      float tq = TQ[tid] + TQ[tid + 64] + TQ[tid + 128] + TQ[tid + 192];
      float m = ts * invCnt;
      float v = tq * invCnt - m * m;
      v = v < 0.f ? 0.f : v;
      float inv = rsqrtf(v + BN_EPS);
      float sc = g[tid] * inv;
      scsh[tid] = sc;
      scsh[64 + tid] = be[tid] - m * sc;
    }
  }
}

// layer-2 GEMM: out[r,64](fp16) = bn1(relu(in+b1))[r,64] @ W2
__global__ void k_gemm2(const __half* __restrict__ in, const float* __restrict__ W,
                        __half* __restrict__ out, int nrows,
                        const float* __restrict__ bias, const float* __restrict__ scsh) {
  constexpr int RT = 64, KC = 64, S = KC + 4;
  __shared__ float ws[KC * 64];
  __shared__ float xs[RT * S];

  int tid = threadIdx.x;
  int row0 = blockIdx.x * RT;
  for (int s = tid; s < KC * 16; s += 256)
    ((float4*)ws)[s] = ((const float4*)W)[s];
  for (int s = tid; s < RT * 16; s += 256) {
    int r = s >> 4, k4 = s & 15;
    int gr = row0 + r;
    int kg = k4 * 4;
    float4 v = make_float4(0.f, 0.f, 0.f, 0.f);
    if (gr < nrows) {
      uint2 u = *(const uint2*)(in + (size_t)gr * 64 + kg);
      float2 fa = __half22float2(u2h(u.x));
      float2 fb = __half22float2(u2h(u.y));
      v = make_float4(fa.x, fa.y, fb.x, fb.y);
    }
    float4 bb = *(const float4*)(bias + kg);
    float4 sc = *(const float4*)(scsh + kg);
    float4 sh = *(const float4*)(scsh + 64 + kg);
    v.x = fmaxf(v.x + bb.x, 0.f) * sc.x + sh.x;
    v.y = fmaxf(v.y + bb.y, 0.f) * sc.y + sh.y;
    v.z = fmaxf(v.z + bb.z, 0.f) * sc.z + sh.z;
    v.w = fmaxf(v.w + bb.w, 0.f) * sc.w + sh.w;
    *(float4*)&xs[r * S + kg] = v;
  }
  __syncthreads();

  int rg = tid >> 4, cg = tid & 15;
  int c0 = cg * 4, r0 = rg * 4;
  float acc[4][4];
#pragma unroll
  for (int i = 0; i < 4; ++i)
#pragma unroll
    for (int j = 0; j < 4; ++j) acc[i][j] = 0.0f;
#pragma unroll 2
  for (int kk = 0; kk < KC; kk += 4) {
    float4 wv0 = *(const float4*)&ws[(kk + 0) * 64 + c0];
    float4 wv1 = *(const float4*)&ws[(kk + 1) * 64 + c0];
    float4 wv2 = *(const float4*)&ws[(kk + 2) * 64 + c0];
    float4 wv3 = *(const float4*)&ws[(kk + 3) * 64 + c0];
#pragma unroll
    for (int i = 0; i < 4; ++i) {
      float4 xv = *(const float4*)&xs[(r0 + i) * S + kk];
      acc[i][0] = fmaf(xv.x, wv0.x, acc[i][0]);
      acc[i][1] = fmaf(xv.x, wv0.y, acc[i][1]);
      acc[i][2] = fmaf(xv.x, wv0.z, acc[i][2]);
      acc[i][3] = fmaf(xv.x, wv0.w, acc[i][3]);
      acc[i][0] = fmaf(xv.y, wv1.x, acc[i][0]);
      acc[i][1] = fmaf(xv.y, wv1.y, acc[i][1]);
      acc[i][2] = fmaf(xv.y, wv1.z, acc[i][2]);
      acc[i][3] = fmaf(xv.y, wv1.w, acc[i][3]);
      acc[i][0] = fmaf(xv.z, wv2.x, acc[i][0]);
      acc[i][1] = fmaf(xv.z, wv2.y, acc[i][1]);
      acc[i][2] = fmaf(xv.z, wv2.z, acc[i][2]);
      acc[i][3] = fmaf(xv.z, wv2.w, acc[i][3]);
      acc[i][0] = fmaf(xv.w, wv3.x, acc[i][0]);
      acc[i][1] = fmaf(xv.w, wv3.y, acc[i][1]);
      acc[i][2] = fmaf(xv.w, wv3.z, acc[i][2]);
      acc[i][3] = fmaf(xv.w, wv3.w, acc[i][3]);
    }
  }
#pragma unroll
  for (int i = 0; i < 4; ++i) {
    int gr = row0 + r0 + i;
    if (gr < nrows) {
      __half2 h01 = __floats2half2_rn(acc[i][0], acc[i][1]);
      __half2 h23 = __floats2half2_rn(acc[i][2], acc[i][3]);
      *(uint2*)(out + (size_t)gr * 64 + c0) = make_uint2(h2u(h01), h2u(h23));
    }
  }
}

// rows are (node,b): r -> out[b*N + node]
__global__ void k_out(const __half* __restrict__ raw, const float* __restrict__ bias,
                      const float* __restrict__ scsh, const float* __restrict__ Wc,
                      const float* __restrict__ bc, float* __restrict__ out,
                      int rows, int N) {
  int row = blockIdx.x * 4 + (threadIdx.x >> 6);
  int c = threadIdx.x & 63;
  if (row >= rows) return;
  float v = fmaxf(__half2float(raw[(size_t)row * 64 + c]) + bias[c], 0.0f)
              * scsh[c] + scsh[64 + c];
  float p = v * Wc[c];
#pragma unroll
  for (int off = 32; off > 0; off >>= 1) p += __shfl_xor(p, off, 64);
  if (c == 0) {
    int node = row >> 1, b = row & 1;
    out[(size_t)b * N + node] = p + bc[0];
  }
}

extern "C" void kernel_launch(void* const* d_in, const int* in_sizes, int n_in,
                              void* d_out, int out_size, void* d_ws, size_t ws_size,
                              hipStream_t stream) {
  const float* x   = (const float*)d_in[0];
  const float* ew  = (const float*)d_in[1];
  const float* W1  = (const float*)d_in[2];
  const float* b1  = (const float*)d_in[3];
  const float* W2  = (const float*)d_in[4];
  const float* b2  = (const float*)d_in[5];
  const float* g1  = (const float*)d_in[6];
  const float* be1 = (const float*)d_in[7];
  const float* g2  = (const float*)d_in[8];
  const float* be2 = (const float*)d_in[9];
  const float* Wc  = (const float*)d_in[10];
  const float* bc  = (const float*)d_in[11];
  const int*   ei  = (const int*)d_in[12];

  const int E  = in_sizes[1];
  const int BN = in_sizes[0] / 128;  // 100000
  const int N  = BN / 2;

  char* w = (char*)d_ws;
  size_t off = 0;
  int*   cnt    = (int*)  (w + off); off += (size_t)N * 4;
  int*   oflc   = (int*)  (w + off); off += 16;
  int*   dbdone = (int*)  (w + off); off += 16;
  int*   adone1 = (int*)  (w + off); off += 16;
  int*   adone2 = (int*)  (w + off); off += 16;
  size_t zbytes = off;               // zeroed region
  float* dinv   = (float*)(w + off); off += (size_t)N * 4;
  float* scsh1  = (float*)(w + off); off += 512;
  float* scsh2  = (float*)(w + off); off += 512;
  int*   ofll   = (int*)  (w + off); off += (size_t)OCAP * 4;
  off = (off + 255) & ~(size_t)255;
  int gA = (N + 3) / 4;              // 12500 agg blocks
  float* pst    = (float*)(w + off); off += (size_t)gA * 128 * 4;
  unsigned* pairs = (unsigned*)(w + off); off += (size_t)N * CAP * 4;
  __half* bufA  = (__half*)(w + off); off += (size_t)BN * 64 * 2;
  __half* bufB  = (__half*)(w + off); off += (size_t)BN * 64 * 2;

  float* out = (float*)d_out;

  hipMemsetAsync(w, 0, zbytes, stream);

  dim3 blk(256);
  int gB = (BN + 63) / 64;          // gemm blocks
  int fB = (E + 255) / 256;         // fill blocks
  int base3 = gB > (fB + 1) / 2 ? gB : (fB + 1) / 2;
  int gMega = 3 * base3;
  int gR  = (BN + 3) / 4;
  float invCnt = 1.0f / (float)BN;

  // ---- fill || layer-1 GEMM ----
  k_mega<<<gMega, blk, 0, stream>>>(x, W1, bufA, BN, N, ew, ei, cnt, pairs,
                                    oflc, ofll, E, gB, fB);
  k_degb<<<gA, blk, 0, stream>>>(pairs, cnt, oflc, dinv, dbdone, N, ew, ei, ofll, E);

  // ---- layer 1: agg + pst partials + finisher-tail scsh ----
  k_agg<<<gA, blk, 0, stream>>>(bufA, pairs, cnt, dinv, bufB, b1, pst, N,
                                adone1, g1, be1, scsh1, invCnt,
                                ew, ei, oflc, ofll, BN, E);

  // ---- layer 2 ----
  k_gemm2<<<gB, blk, 0, stream>>>(bufB, W2, bufA, BN, b1, scsh1);
  k_agg<<<gA, blk, 0, stream>>>(bufA, pairs, cnt, dinv, bufB, b2, pst, N,
                                adone2, g2, be2, scsh2, invCnt,
                                ew, ei, oflc, ofll, BN, E);

  // ---- head ----
  k_out<<<gR, blk, 0, stream>>>(bufB, b2, scsh2, Wc, bc, out, BN, N);
}

// Round 12
// 348.933 us; speedup vs baseline: 7.0138x; 7.0138x over previous
//
#include <hip/hip_runtime.h>
#include <hip/hip_fp16.h>
#include <cstdint>
#include <cstddef>

// GCN_EW: 2-layer GCN, exp edge weights, gcn_norm w/ self-loops, training BN,
// 64->1 head.  B=2, N=50000, E=800000, IN=128, HID=64.
//
// R12 = R10 restored (348us proven best). R11's finisher-tail spin regressed
// 7x: spinning on a device-scope atomic counter costs ~1ms at 12500 blocks
// (matches R8's grid.sync ~100us/barrier at 1024 blocks). LAW: kernel
// boundaries (~5-10us) are the only cheap cross-block sync on MI355X;
// fence+counter last-block (no waiting) is OK, spin-waiting is never OK.
// Atomic pipe ceiling ~17 G/s (measured 3x) also rules out per-block
// atomic stats (1.6M atomics = 94us pipe time).
// Structure:
//  - k_mega: role-striped fill (atomic-pipe-bound, ~48us floor) + layer-1
//    GEMM (64-row tile, 4x4 micro-tile, W+x in LDS).
//  - k_degb: bucket-scan degree, wave/node; last-block overflow slow path.
//  - k_agg: 1 node/wave, 12+4-deep gather unroll, 12500 blocks, fp16
//    batch-fused rows [node][b][64]; per-block BN partials -> pst (stores).
//  - k_scsh: 64 blocks reduce pst -> scale/shift; last-block overflow
//    slow path (CAS fixes + exact recompute; never taken for this input).
//  - k_gemm2 (BN1 fused into staging), k_out (BN2 + head dot fused).
// Row order r = node*2 + b (batch-fused gather, fp16 intermediates).

#define CAP  64
#define OCAP 65536
#define BN_EPS 1e-5f

static __device__ __forceinline__ unsigned h2u(__half2 h) {
  union { __half2 h; unsigned u; } c; c.h = h; return c.u;
}
static __device__ __forceinline__ __half2 u2h(unsigned u) {
  union { unsigned u; __half2 h; } c; c.u = u; return c.h;
}
static __device__ __forceinline__ unsigned pack_pair(int src, float w) {
  __half hw = __float2half_rn(w);
  union { __half h; unsigned short s; } c; c.h = hw;
  return ((unsigned)src << 16) | c.s;
}
static __device__ __forceinline__ float pair_w(unsigned p) {
  union { unsigned short s; __half h; } c; c.s = (unsigned short)(p & 0xFFFFu);
  return __half2float(c.h);
}

// ---- mega: role-striped fill (1 edge/thread) + layer-1 GEMM ----
__global__ void k_mega(const float* __restrict__ x, const float* __restrict__ W,
                       __half* __restrict__ out, int nrows, int N,
                       const float* __restrict__ ew, const int* __restrict__ ei,
                       int* __restrict__ cnt, unsigned* __restrict__ pairs,
                       int* __restrict__ ofl_cnt, int* __restrict__ ofl_list,
                       int E, int gemmBlocks, int fillBlocks) {
  constexpr int RT = 64, KC = 64, S = KC + 4;
  __shared__ float ws[KC * 64];
  __shared__ float xs[RT * S];

  int bid = blockIdx.x;
  int tid = threadIdx.x;
  int role = bid % 3;

  if (role == 0) {
    int gid = bid / 3;
    if (gid >= gemmBlocks) return;
    int row0 = gid * RT;
    int rg = tid >> 4, cg = tid & 15;
    int c0 = cg * 4, r0 = rg * 4;
    float acc[4][4];
#pragma unroll
    for (int i = 0; i < 4; ++i)
#pragma unroll
      for (int j = 0; j < 4; ++j) acc[i][j] = 0.0f;

    for (int ch = 0; ch < 2; ++ch) {
      if (ch) __syncthreads();
      const float4* Wp = (const float4*)(W + (size_t)ch * KC * 64);
      for (int s = tid; s < KC * 16; s += 256)
        ((float4*)ws)[s] = Wp[s];
      for (int s = tid; s < RT * 16; s += 256) {
        int r = s >> 4, k4 = s & 15;
        int gr = row0 + r;
        float4 v = make_float4(0.f, 0.f, 0.f, 0.f);
        if (gr < nrows)
          v = *(const float4*)(x + (size_t)gr * 128 + ch * KC + k4 * 4);
        *(float4*)&xs[r * S + k4 * 4] = v;
      }
      __syncthreads();
#pragma unroll 2
      for (int kk = 0; kk < KC; kk += 4) {
        float4 wv0 = *(const float4*)&ws[(kk + 0) * 64 + c0];
        float4 wv1 = *(const float4*)&ws[(kk + 1) * 64 + c0];
        float4 wv2 = *(const float4*)&ws[(kk + 2) * 64 + c0];
        float4 wv3 = *(const float4*)&ws[(kk + 3) * 64 + c0];
#pragma unroll
        for (int i = 0; i < 4; ++i) {
          float4 xv = *(const float4*)&xs[(r0 + i) * S + kk];
          acc[i][0] = fmaf(xv.x, wv0.x, acc[i][0]);
          acc[i][1] = fmaf(xv.x, wv0.y, acc[i][1]);
          acc[i][2] = fmaf(xv.x, wv0.z, acc[i][2]);
          acc[i][3] = fmaf(xv.x, wv0.w, acc[i][3]);
          acc[i][0] = fmaf(xv.y, wv1.x, acc[i][0]);
          acc[i][1] = fmaf(xv.y, wv1.y, acc[i][1]);
          acc[i][2] = fmaf(xv.y, wv1.z, acc[i][2]);
          acc[i][3] = fmaf(xv.y, wv1.w, acc[i][3]);
          acc[i][0] = fmaf(xv.z, wv2.x, acc[i][0]);
          acc[i][1] = fmaf(xv.z, wv2.y, acc[i][1]);
          acc[i][2] = fmaf(xv.z, wv2.z, acc[i][2]);
          acc[i][3] = fmaf(xv.z, wv2.w, acc[i][3]);
          acc[i][0] = fmaf(xv.w, wv3.x, acc[i][0]);
          acc[i][1] = fmaf(xv.w, wv3.y, acc[i][1]);
          acc[i][2] = fmaf(xv.w, wv3.z, acc[i][2]);
          acc[i][3] = fmaf(xv.w, wv3.w, acc[i][3]);
        }
      }
    }
#pragma unroll
    for (int i = 0; i < 4; ++i) {
      int gr = row0 + r0 + i;
      if (gr < nrows) {
        int orow = (gr < N) ? gr * 2 : (gr - N) * 2 + 1;
        __half2 h01 = __floats2half2_rn(acc[i][0], acc[i][1]);
        __half2 h23 = __floats2half2_rn(acc[i][2], acc[i][3]);
        *(uint2*)(out + (size_t)orow * 64 + c0) = make_uint2(h2u(h01), h2u(h23));
      }
    }
  } else {
    int fid = (bid / 3) * 2 + role - 1;
    if (fid >= fillBlocks) return;
    int e = fid * 256 + tid;
    if (e >= E) return;
    int r = ei[e];
    int c = ei[(size_t)E + e];
    float w = expf(ew[e]);
    int pos = atomicAdd(&cnt[c], 1);
    if (pos < CAP) {
      pairs[(size_t)c * CAP + pos] = pack_pair(r, w);
    } else {
      int o = atomicAdd(ofl_cnt, 1);
      if (o < OCAP) ofl_list[o] = e;
    }
  }
}

// dinv[node] = rsqrt(1+sum expw); done-counter last block handles the
// overflow slow path (adds + rsqrt) -- uniform no-op when tot==0.
__global__ void k_degb(const unsigned* __restrict__ pairs, const int* __restrict__ cnt,
                       const int* __restrict__ ofl_cnt, float* __restrict__ deg,
                       int* __restrict__ done, int N,
                       const float* __restrict__ ew, const int* __restrict__ ei,
                       const int* __restrict__ ofl_list, int E) {
  int tid = threadIdx.x;
  int node = blockIdx.x * 4 + (tid >> 6);
  int lane = tid & 63;
  int tot = *ofl_cnt;
  if (node < N) {
    int n = cnt[node];
    n = n > CAP ? CAP : n;
    float v = 0.0f;
    if (lane < n) v = pair_w(pairs[(size_t)node * CAP + lane]);
#pragma unroll
    for (int off = 32; off > 0; off >>= 1) v += __shfl_xor(v, off, 64);
    if (lane == 0) deg[node] = (tot == 0) ? rsqrtf(v + 1.0f) : (v + 1.0f);
  }
  if (tot == 0) return;                 // fast path: done
  if (tot > OCAP) tot = OCAP;
  __shared__ int isLast;
  __threadfence();
  if (tid == 0) isLast = (atomicAdd(done, 1) == (int)gridDim.x - 1);
  __syncthreads();
  if (!isLast) return;
  for (int i = tid; i < tot; i += 256) {
    int e = ofl_list[i];
    atomicAdd(&deg[ei[(size_t)E + e]], expf(ew[e]));
  }
  __threadfence();
  __syncthreads();
  for (int i = tid; i < N; i += 256) deg[i] = rsqrtf(deg[i]);
}

// ---- agg: R7 loop (1 node/wave, 12+4) + per-block stats partials -> pst ----
__global__ void k_agg(const __half* __restrict__ h, const unsigned* __restrict__ pairs,
                      const int* __restrict__ cnt, const float* __restrict__ dinv,
                      __half* __restrict__ raw, const float* __restrict__ bias,
                      float* __restrict__ pst, int N) {
  __shared__ float Ss[64][9], Qq[64][9];
  const int tid = threadIdx.x, lane = tid & 63;
  int node = blockIdx.x * 4 + (tid >> 6);
  const __half2* hv = (const __half2*)h;
  int ch0 = 2 * (lane & 31);
  float sx = 0.f, sy = 0.f, qx = 0.f, qy = 0.f;

  if (node < N) {
    float dc = dinv[node];
    float2 self = __half22float2(hv[(size_t)node * 64 + lane]);
    float ax = self.x * dc, ay = self.y * dc;
    int n = cnt[node];
    n = n > CAP ? CAP : n;
    const unsigned* pp = pairs + (size_t)node * CAP;
    int k = 0;
    for (; k + 12 <= n; k += 12) {
      unsigned pr[12];
#pragma unroll
      for (int q = 0; q < 12; ++q) pr[q] = pp[k + q];
      float dr[12];
#pragma unroll
      for (int q = 0; q < 12; ++q) dr[q] = dinv[pr[q] >> 16];
      __half2 v[12];
#pragma unroll
      for (int q = 0; q < 12; ++q) v[q] = hv[(size_t)(pr[q] >> 16) * 64 + lane];
#pragma unroll
      for (int q = 0; q < 12; ++q) {
        float w = pair_w(pr[q]) * dr[q];
        float2 f = __half22float2(v[q]);
        ax = fmaf(w, f.x, ax);
        ay = fmaf(w, f.y, ay);
      }
    }
    for (; k + 4 <= n; k += 4) {
      unsigned pr[4];
#pragma unroll
      for (int q = 0; q < 4; ++q) pr[q] = pp[k + q];
      float dr[4];
#pragma unroll
      for (int q = 0; q < 4; ++q) dr[q] = dinv[pr[q] >> 16];
      __half2 v[4];
#pragma unroll
      for (int q = 0; q < 4; ++q) v[q] = hv[(size_t)(pr[q] >> 16) * 64 + lane];
#pragma unroll
      for (int q = 0; q < 4; ++q) {
        float w = pair_w(pr[q]) * dr[q];
        float2 f = __half22float2(v[q]);
        ax = fmaf(w, f.x, ax);
        ay = fmaf(w, f.y, ay);
      }
    }
    for (; k < n; ++k) {
      unsigned pr = pp[k];
      float w = pair_w(pr) * dinv[pr >> 16];
      float2 f = __half22float2(hv[(size_t)(pr >> 16) * 64 + lane]);
      ax = fmaf(w, f.x, ax);
      ay = fmaf(w, f.y, ay);
    }
    __half2 r = __floats2half2_rn(ax * dc, ay * dc);
    ((__half2*)raw)[(size_t)node * 64 + lane] = r;
    float2 f = __half22float2(r);          // stats on stored (rounded) values
    float bb0 = bias[ch0], bb1 = bias[ch0 + 1];
    float y0 = fmaxf(f.x + bb0, 0.f), y1 = fmaxf(f.y + bb1, 0.f);
    sx = y0; qx = y0 * y0; sy = y1; qy = y1 * y1;
  }

  int j = tid >> 5;                        // 8 groups; (ch0,j) writer unique
  Ss[ch0][j] = sx; Ss[ch0 + 1][j] = sy;
  Qq[ch0][j] = qx; Qq[ch0 + 1][j] = qy;
  __syncthreads();
  if (tid < 64) {
    float s = 0.f, q = 0.f;
#pragma unroll
    for (int u = 0; u < 8; ++u) { s += Ss[tid][u]; q += Qq[tid][u]; }
    pst[(size_t)blockIdx.x * 128 + tid] = s;
    pst[(size_t)blockIdx.x * 128 + 64 + tid] = q;
  }
}

// ---- scsh: 64 blocks (1/channel) reduce pst; done-counter last block
// carries the exact overflow slow path (CAS fix + full recompute). ----
__global__ void k_scsh(const float* __restrict__ pst, int nblk,
                       const float* __restrict__ g, const float* __restrict__ be,
                       float* __restrict__ scsh, int* __restrict__ done, float invCnt,
                       const float* __restrict__ ew, const int* __restrict__ ei,
                       const float* __restrict__ dinv, const int* __restrict__ ofl_cnt,
                       const int* __restrict__ ofl_list,
                       const __half* __restrict__ h, __half* __restrict__ raw,
                       const float* __restrict__ bias, int rows, int E) {
  __shared__ float S[256], Q[256];
  __shared__ int isLast;
  int tid = threadIdx.x, ch = blockIdx.x;
  float s = 0.f, q = 0.f;
  for (int b = tid; b < nblk; b += 256) {
    s += pst[(size_t)b * 128 + ch];
    q += pst[(size_t)b * 128 + 64 + ch];
  }
  S[tid] = s; Q[tid] = q;
  __syncthreads();
  for (int o = 128; o; o >>= 1) {
    if (tid < o) { S[tid] += S[tid + o]; Q[tid] += Q[tid + o]; }
    __syncthreads();
  }
  if (tid == 0) {
    float m = S[0] * invCnt;
    float v = Q[0] * invCnt - m * m;
    v = v < 0.f ? 0.f : v;
    float inv = rsqrtf(v + BN_EPS);
    float sc = g[ch] * inv;
    scsh[ch] = sc;
    scsh[64 + ch] = be[ch] - m * sc;
  }
  int tot = *ofl_cnt;
  if (tot == 0) return;                  // fast path
  if (tot > OCAP) tot = OCAP;
  __threadfence();
  if (tid == 0) isLast = (atomicAdd(done, 1) == (int)gridDim.x - 1);
  __syncthreads();
  if (!isLast) return;
  // slow path (never taken for this input): CAS fix + full stats recompute
  for (int i = tid; i < tot; i += 256) {
    int e = ofl_list[i];
    int r = ei[e], c = ei[(size_t)E + e];
    float nrm = dinv[r] * expf(ew[e]) * dinv[c];
    const __half2* hr = (const __half2*)(h + (size_t)r * 128);
    unsigned* dst = (unsigned*)(raw + (size_t)c * 128);
    for (int jj = 0; jj < 64; ++jj) {
      float2 hv2 = __half22float2(hr[jj]);
      unsigned old = dst[jj], assumed;
      do {
        assumed = old;
        float2 cur = __half22float2(u2h(assumed));
        __half2 nv = __floats2half2_rn(cur.x + nrm * hv2.x, cur.y + nrm * hv2.y);
        old = atomicCAS(&dst[jj], assumed, h2u(nv));
      } while (old != assumed);
    }
  }
  __threadfence();
  __syncthreads();
  int c = tid & 63, rg = tid >> 6;
  float s2 = 0.f, q2 = 0.f;
  for (int r = rg; r < rows; r += 4) {
    float y = fmaxf(__half2float(raw[(size_t)r * 64 + c]) + bias[c], 0.f);
    s2 += y; q2 += y * y;
  }
  S[tid] = s2; Q[tid] = q2;
  __syncthreads();
  if (tid < 64) {
    float ts = S[tid] + S[tid + 64] + S[tid + 128] + S[tid + 192];
    float tq = Q[tid] + Q[tid + 64] + Q[tid + 128] + Q[tid + 192];
    float m = ts * invCnt;
    float v = tq * invCnt - m * m;
    v = v < 0.f ? 0.f : v;
    float inv = rsqrtf(v + BN_EPS);
    float sc = g[tid] * inv;
    scsh[tid] = sc;
    scsh[64 + tid] = be[tid] - m * sc;
  }
}

// layer-2 GEMM: out[r,64](fp16) = bn1(relu(in+b1))[r,64] @ W2
__global__ void k_gemm2(const __half* __restrict__ in, const float* __restrict__ W,
                        __half* __restrict__ out, int nrows,
                        const float* __restrict__ bias, const float* __restrict__ scsh) {
  constexpr int RT = 64, KC = 64, S = KC + 4;
  __shared__ float ws[KC * 64];
  __shared__ float xs[RT * S];

  int tid = threadIdx.x;
  int row0 = blockIdx.x * RT;
  for (int s = tid; s < KC * 16; s += 256)
    ((float4*)ws)[s] = ((const float4*)W)[s];
  for (int s = tid; s < RT * 16; s += 256) {
    int r = s >> 4, k4 = s & 15;
    int gr = row0 + r;
    int kg = k4 * 4;
    float4 v = make_float4(0.f, 0.f, 0.f, 0.f);
    if (gr < nrows) {
      uint2 u = *(const uint2*)(in + (size_t)gr * 64 + kg);
      float2 fa = __half22float2(u2h(u.x));
      float2 fb = __half22float2(u2h(u.y));
      v = make_float4(fa.x, fa.y, fb.x, fb.y);
    }
    float4 bb = *(const float4*)(bias + kg);
    float4 sc = *(const float4*)(scsh + kg);
    float4 sh = *(const float4*)(scsh + 64 + kg);
    v.x = fmaxf(v.x + bb.x, 0.f) * sc.x + sh.x;
    v.y = fmaxf(v.y + bb.y, 0.f) * sc.y + sh.y;
    v.z = fmaxf(v.z + bb.z, 0.f) * sc.z + sh.z;
    v.w = fmaxf(v.w + bb.w, 0.f) * sc.w + sh.w;
    *(float4*)&xs[r * S + kg] = v;
  }
  __syncthreads();

  int rg = tid >> 4, cg = tid & 15;
  int c0 = cg * 4, r0 = rg * 4;
  float acc[4][4];
#pragma unroll
  for (int i = 0; i < 4; ++i)
#pragma unroll
    for (int j = 0; j < 4; ++j) acc[i][j] = 0.0f;
#pragma unroll 2
  for (int kk = 0; kk < KC; kk += 4) {
    float4 wv0 = *(const float4*)&ws[(kk + 0) * 64 + c0];
    float4 wv1 = *(const float4*)&ws[(kk + 1) * 64 + c0];
    float4 wv2 = *(const float4*)&ws[(kk + 2) * 64 + c0];
    float4 wv3 = *(const float4*)&ws[(kk + 3) * 64 + c0];
#pragma unroll
    for (int i = 0; i < 4; ++i) {
      float4 xv = *(const float4*)&xs[(r0 + i) * S + kk];
      acc[i][0] = fmaf(xv.x, wv0.x, acc[i][0]);
      acc[i][1] = fmaf(xv.x, wv0.y, acc[i][1]);
      acc[i][2] = fmaf(xv.x, wv0.z, acc[i][2]);
      acc[i][3] = fmaf(xv.x, wv0.w, acc[i][3]);
      acc[i][0] = fmaf(xv.y, wv1.x, acc[i][0]);
      acc[i][1] = fmaf(xv.y, wv1.y, acc[i][1]);
      acc[i][2] = fmaf(xv.y, wv1.z, acc[i][2]);
      acc[i][3] = fmaf(xv.y, wv1.w, acc[i][3]);
      acc[i][0] = fmaf(xv.z, wv2.x, acc[i][0]);
      acc[i][1] = fmaf(xv.z, wv2.y, acc[i][1]);
      acc[i][2] = fmaf(xv.z, wv2.z, acc[i][2]);
      acc[i][3] = fmaf(xv.z, wv2.w, acc[i][3]);
      acc[i][0] = fmaf(xv.w, wv3.x, acc[i][0]);
      acc[i][1] = fmaf(xv.w, wv3.y, acc[i][1]);
      acc[i][2] = fmaf(xv.w, wv3.z, acc[i][2]);
      acc[i][3] = fmaf(xv.w, wv3.w, acc[i][3]);
    }
  }
#pragma unroll
  for (int i = 0; i < 4; ++i) {
    int gr = row0 + r0 + i;
    if (gr < nrows) {
      __half2 h01 = __floats2half2_rn(acc[i][0], acc[i][1]);
      __half2 h23 = __floats2half2_rn(acc[i][2], acc[i][3]);
      *(uint2*)(out + (size_t)gr * 64 + c0) = make_uint2(h2u(h01), h2u(h23));
    }
  }
}

// rows are (node,b): r -> out[b*N + node]
__global__ void k_out(const __half* __restrict__ raw, const float* __restrict__ bias,
                      const float* __restrict__ scsh, const float* __restrict__ Wc,
                      const float* __restrict__ bc, float* __restrict__ out,
                      int rows, int N) {
  int row = blockIdx.x * 4 + (threadIdx.x >> 6);
  int c = threadIdx.x & 63;
  if (row >= rows) return;
  float v = fmaxf(__half2float(raw[(size_t)row * 64 + c]) + bias[c], 0.0f)
              * scsh[c] + scsh[64 + c];
  float p = v * Wc[c];
#pragma unroll
  for (int off = 32; off > 0; off >>= 1) p += __shfl_xor(p, off, 64);
  if (c == 0) {
    int node = row >> 1, b = row & 1;
    out[(size_t)b * N + node] = p + bc[0];
  }
}

extern "C" void kernel_launch(void* const* d_in, const int* in_sizes, int n_in,
                              void* d_out, int out_size, void* d_ws, size_t ws_size,
                              hipStream_t stream) {
  const float* x   = (const float*)d_in[0];
  const float* ew  = (const float*)d_in[1];
  const float* W1  = (const float*)d_in[2];
  const float* b1  = (const float*)d_in[3];
  const float* W2  = (const float*)d_in[4];
  const float* b2  = (const float*)d_in[5];
  const float* g1  = (const float*)d_in[6];
  const float* be1 = (const float*)d_in[7];
  const float* g2  = (const float*)d_in[8];
  const float* be2 = (const float*)d_in[9];
  const float* Wc  = (const float*)d_in[10];
  const float* bc  = (const float*)d_in[11];
  const int*   ei  = (const int*)d_in[12];

  const int E  = in_sizes[1];
  const int BN = in_sizes[0] / 128;  // 100000
  const int N  = BN / 2;

  char* w = (char*)d_ws;
  size_t off = 0;
  int*   cnt    = (int*)  (w + off); off += (size_t)N * 4;
  int*   oflc   = (int*)  (w + off); off += 16;
  int*   dbdone = (int*)  (w + off); off += 16;
  int*   sdone1 = (int*)  (w + off); off += 16;
  int*   sdone2 = (int*)  (w + off); off += 16;
  size_t zbytes = off;               // zeroed region
  float* dinv   = (float*)(w + off); off += (size_t)N * 4;
  float* scsh1  = (float*)(w + off); off += 512;
  float* scsh2  = (float*)(w + off); off += 512;
  int*   ofll   = (int*)  (w + off); off += (size_t)OCAP * 4;
  off = (off + 255) & ~(size_t)255;
  int gA = (N + 3) / 4;              // 12500 agg blocks
  float* pst    = (float*)(w + off); off += (size_t)gA * 128 * 4;
  unsigned* pairs = (unsigned*)(w + off); off += (size_t)N * CAP * 4;
  __half* bufA  = (__half*)(w + off); off += (size_t)BN * 64 * 2;
  __half* bufB  = (__half*)(w + off); off += (size_t)BN * 64 * 2;

  float* out = (float*)d_out;

  hipMemsetAsync(w, 0, zbytes, stream);

  dim3 blk(256);
  int gB = (BN + 63) / 64;          // gemm blocks
  int fB = (E + 255) / 256;         // fill blocks
  int base3 = gB > (fB + 1) / 2 ? gB : (fB + 1) / 2;
  int gMega = 3 * base3;
  int gR  = (BN + 3) / 4;
  float invCnt = 1.0f / (float)BN;

  // ---- fill || layer-1 GEMM ----
  k_mega<<<gMega, blk, 0, stream>>>(x, W1, bufA, BN, N, ew, ei, cnt, pairs,
                                    oflc, ofll, E, gB, fB);
  k_degb<<<gA, blk, 0, stream>>>(pairs, cnt, oflc, dinv, dbdone, N, ew, ei, ofll, E);

  // ---- layer 1: agg (+pst partials) -> scsh ----
  k_agg<<<gA, blk, 0, stream>>>(bufA, pairs, cnt, dinv, bufB, b1, pst, N);
  k_scsh<<<64, blk, 0, stream>>>(pst, gA, g1, be1, scsh1, sdone1, invCnt,
                                 ew, ei, dinv, oflc, ofll, bufA, bufB, b1, BN, E);

  // ---- layer 2 ----
  k_gemm2<<<gB, blk, 0, stream>>>(bufB, W2, bufA, BN, b1, scsh1);
  k_agg<<<gA, blk, 0, stream>>>(bufA, pairs, cnt, dinv, bufB, b2, pst, N);
  k_scsh<<<64, blk, 0, stream>>>(pst, gA, g2, be2, scsh2, sdone2, invCnt,
                                 ew, ei, dinv, oflc, ofll, bufA, bufB, b2, BN, E);

  // ---- head ----
  k_out<<<gR, blk, 0, stream>>>(bufB, b2, scsh2, Wc, bc, out, BN, N);
}